// Round 10
// baseline (724.756 us; speedup 1.0000x reference)
//
#include <hip/hip_runtime.h>

#define BATCH 256
#define TLEN  512
#define DIN   64
#define HID   128
#define NOUT  40
#define SC    16
#define NCH   (TLEN / SC)   // 32 chunks per layer

typedef _Float16 f16x8 __attribute__((ext_vector_type(8)));
typedef float    f32x4 __attribute__((ext_vector_type(4)));

#define MFMA16(a, b, c) __builtin_amdgcn_mfma_f32_16x16x32_f16((a), (b), (c), 0, 0, 0)

// LDS-visibility barrier only: no vmcnt drain.
#define BARRIER() do {                                      \
    asm volatile("s_waitcnt lgkmcnt(0)" ::: "memory");      \
    __builtin_amdgcn_s_barrier();                           \
} while (0)

static __device__ __forceinline__ f16x8 pack8(float4 a, float4 b) {
    f16x8 v;
    v[0] = (_Float16)a.x; v[1] = (_Float16)a.y; v[2] = (_Float16)a.z; v[3] = (_Float16)a.w;
    v[4] = (_Float16)b.x; v[5] = (_Float16)b.y; v[6] = (_Float16)b.z; v[7] = (_Float16)b.w;
    return v;
}
static __device__ __forceinline__ float sig_(float x) {
    return __builtin_amdgcn_rcpf(1.0f + __expf(-x));
}
static __device__ __forceinline__ float tanh_(float x) {
    return fmaf(-2.0f, __builtin_amdgcn_rcpf(__expf(2.0f * x) + 1.0f), 1.0f);
}
static __device__ __forceinline__ f32x4 splat4(float v) { return (f32x4){v, v, v, v}; }

// Weight fragment loader; uses kernel-local `kg`. k = kt*32 + kg*8 + j.
#define LD8(base, g, K, kt) pack8(*(const float4*)((base) + (size_t)(g) * (K) + (kt) * 32 + kg * 8), \
                                  *(const float4*)((base) + (size_t)(g) * (K) + (kt) * 32 + kg * 8 + 4))

// ============ Fused 2-layer LSTM, layer-1 staggered one chunk behind ============
// 256 blocks (one batch each) x 512 thr (8 waves). Wave w owns hid [w*16,w*16+16)
// for BOTH layers. Per chunk: GEMM phase precomputes xacc (l0 input proj, chunk c)
// and yacc (l1 input proj from y0buf of chunk c-1). Steady step: 16 l0-h-MFMA +
// 16 l1-h-MFMA (independent -> pipe overlap), both ACTs, one barrier.
__global__ void __attribute__((amdgpu_flat_work_group_size(512, 512), amdgpu_waves_per_eu(2, 2)))
lstm_fused(const float* __restrict__ x,
           const float* __restrict__ Wih0, const float* __restrict__ Whh0,
           const float* __restrict__ bih0, const float* __restrict__ bhh0,
           const float* __restrict__ Wih1, const float* __restrict__ Whh1,
           const float* __restrict__ bih1, const float* __restrict__ bhh1,
           const float* __restrict__ Wfc,  const float* __restrict__ bfc,
           float* __restrict__ out)
{
    const int b    = blockIdx.x;
    const int tid  = threadIdx.x;
    const int lane = tid & 63, wave = tid >> 6;
    const int col  = lane & 15, kg = lane >> 4;
    const int hid  = wave * 16 + col;

    __shared__ __align__(16) float    xacc[SC * HID * 4];    // 32 KB
    __shared__ __align__(16) float    yacc[SC * HID * 4];    // 32 KB
    __shared__ __align__(16) _Float16 h0_lds[2][HID];
    __shared__ __align__(16) _Float16 h1_lds[2][HID];
    __shared__ __align__(16) _Float16 y0buf[2][SC][HID];     // 8 KB ring

    // ---- held recurrent weights (AGPR-pinned): 32 frags = 128 regs ----
    f16x8 Wh0_00 = LD8(Whh0, 0 * HID + hid, HID, 0), Wh0_01 = LD8(Whh0, 0 * HID + hid, HID, 1);
    f16x8 Wh0_02 = LD8(Whh0, 0 * HID + hid, HID, 2), Wh0_03 = LD8(Whh0, 0 * HID + hid, HID, 3);
    f16x8 Wh0_10 = LD8(Whh0, 1 * HID + hid, HID, 0), Wh0_11 = LD8(Whh0, 1 * HID + hid, HID, 1);
    f16x8 Wh0_12 = LD8(Whh0, 1 * HID + hid, HID, 2), Wh0_13 = LD8(Whh0, 1 * HID + hid, HID, 3);
    f16x8 Wh0_20 = LD8(Whh0, 2 * HID + hid, HID, 0), Wh0_21 = LD8(Whh0, 2 * HID + hid, HID, 1);
    f16x8 Wh0_22 = LD8(Whh0, 2 * HID + hid, HID, 2), Wh0_23 = LD8(Whh0, 2 * HID + hid, HID, 3);
    f16x8 Wh0_30 = LD8(Whh0, 3 * HID + hid, HID, 0), Wh0_31 = LD8(Whh0, 3 * HID + hid, HID, 1);
    f16x8 Wh0_32 = LD8(Whh0, 3 * HID + hid, HID, 2), Wh0_33 = LD8(Whh0, 3 * HID + hid, HID, 3);
    f16x8 Wh1_00 = LD8(Whh1, 0 * HID + hid, HID, 0), Wh1_01 = LD8(Whh1, 0 * HID + hid, HID, 1);
    f16x8 Wh1_02 = LD8(Whh1, 0 * HID + hid, HID, 2), Wh1_03 = LD8(Whh1, 0 * HID + hid, HID, 3);
    f16x8 Wh1_10 = LD8(Whh1, 1 * HID + hid, HID, 0), Wh1_11 = LD8(Whh1, 1 * HID + hid, HID, 1);
    f16x8 Wh1_12 = LD8(Whh1, 1 * HID + hid, HID, 2), Wh1_13 = LD8(Whh1, 1 * HID + hid, HID, 3);
    f16x8 Wh1_20 = LD8(Whh1, 2 * HID + hid, HID, 0), Wh1_21 = LD8(Whh1, 2 * HID + hid, HID, 1);
    f16x8 Wh1_22 = LD8(Whh1, 2 * HID + hid, HID, 2), Wh1_23 = LD8(Whh1, 2 * HID + hid, HID, 3);
    f16x8 Wh1_30 = LD8(Whh1, 3 * HID + hid, HID, 0), Wh1_31 = LD8(Whh1, 3 * HID + hid, HID, 1);
    f16x8 Wh1_32 = LD8(Whh1, 3 * HID + hid, HID, 2), Wh1_33 = LD8(Whh1, 3 * HID + hid, HID, 3);
    asm("" : "+a"(Wh0_00), "+a"(Wh0_01), "+a"(Wh0_02), "+a"(Wh0_03),
             "+a"(Wh0_10), "+a"(Wh0_11), "+a"(Wh0_12), "+a"(Wh0_13));
    asm("" : "+a"(Wh0_20), "+a"(Wh0_21), "+a"(Wh0_22), "+a"(Wh0_23),
             "+a"(Wh0_30), "+a"(Wh0_31), "+a"(Wh0_32), "+a"(Wh0_33));
    asm("" : "+a"(Wh1_00), "+a"(Wh1_01), "+a"(Wh1_02), "+a"(Wh1_03),
             "+a"(Wh1_10), "+a"(Wh1_11), "+a"(Wh1_12), "+a"(Wh1_13));
    asm("" : "+a"(Wh1_20), "+a"(Wh1_21), "+a"(Wh1_22), "+a"(Wh1_23),
             "+a"(Wh1_30), "+a"(Wh1_31), "+a"(Wh1_32), "+a"(Wh1_33));

    const float bs00 = bih0[0 * HID + hid] + bhh0[0 * HID + hid];
    const float bs01 = bih0[1 * HID + hid] + bhh0[1 * HID + hid];
    const float bs02 = bih0[2 * HID + hid] + bhh0[2 * HID + hid];
    const float bs03 = bih0[3 * HID + hid] + bhh0[3 * HID + hid];
    const float bs10 = bih1[0 * HID + hid] + bhh1[0 * HID + hid];
    const float bs11 = bih1[1 * HID + hid] + bhh1[1 * HID + hid];
    const float bs12 = bih1[2 * HID + hid] + bhh1[2 * HID + hid];
    const float bs13 = bih1[3 * HID + hid] + bhh1[3 * HID + hid];

    float cc0 = 0.f, hv0 = 0.f, cc1 = 0.f, hv1 = 0.f;
    if (kg == 0) { h0_lds[0][hid] = (_Float16)0.f; h1_lds[0][hid] = (_Float16)0.f; }

    const float* xA = x + (size_t)b * TLEN * DIN + (size_t)col * DIN + kg * 8;

// ---- input-projection GEMMs (M = 16 timesteps) ----
#define XPROJ(C) do {                                                            \
    f16x8 Wx00 = LD8(Wih0, 0 * HID + hid, DIN, 0), Wx01 = LD8(Wih0, 0 * HID + hid, DIN, 1); \
    f16x8 Wx10 = LD8(Wih0, 1 * HID + hid, DIN, 0), Wx11 = LD8(Wih0, 1 * HID + hid, DIN, 1); \
    f16x8 Wx20 = LD8(Wih0, 2 * HID + hid, DIN, 0), Wx21 = LD8(Wih0, 2 * HID + hid, DIN, 1); \
    f16x8 Wx30 = LD8(Wih0, 3 * HID + hid, DIN, 0), Wx31 = LD8(Wih0, 3 * HID + hid, DIN, 1); \
    const float* pa = xA + (size_t)(C) * SC * DIN;                               \
    f16x8 A0 = pack8(*(const float4*)pa,        *(const float4*)(pa + 4));       \
    f16x8 A1 = pack8(*(const float4*)(pa + 32), *(const float4*)(pa + 36));      \
    f32x4 g0 = splat4(bs00), g1 = splat4(bs01), g2 = splat4(bs02), g3 = splat4(bs03); \
    g0 = MFMA16(A0, Wx00, g0); g1 = MFMA16(A0, Wx10, g1);                        \
    g2 = MFMA16(A0, Wx20, g2); g3 = MFMA16(A0, Wx30, g3);                        \
    g0 = MFMA16(A1, Wx01, g0); g1 = MFMA16(A1, Wx11, g1);                        \
    g2 = MFMA16(A1, Wx21, g2); g3 = MFMA16(A1, Wx31, g3);                        \
    _Pragma("unroll") for (int r = 0; r < 4; ++r) {                              \
        float* d = &xacc[((kg * 4 + r) * HID + hid) * 4];                        \
        d[0] = g0[r]; d[1] = g1[r]; d[2] = g2[r]; d[3] = g3[r];                  \
    }                                                                            \
} while (0)

#define YPROJ(C) do {                                                            \
    f16x8 Wy00 = LD8(Wih1, 0 * HID + hid, HID, 0), Wy01 = LD8(Wih1, 0 * HID + hid, HID, 1); \
    f16x8 Wy02 = LD8(Wih1, 0 * HID + hid, HID, 2), Wy03 = LD8(Wih1, 0 * HID + hid, HID, 3); \
    f16x8 Wy10 = LD8(Wih1, 1 * HID + hid, HID, 0), Wy11 = LD8(Wih1, 1 * HID + hid, HID, 1); \
    f16x8 Wy12 = LD8(Wih1, 1 * HID + hid, HID, 2), Wy13 = LD8(Wih1, 1 * HID + hid, HID, 3); \
    f16x8 Wy20 = LD8(Wih1, 2 * HID + hid, HID, 0), Wy21 = LD8(Wih1, 2 * HID + hid, HID, 1); \
    f16x8 Wy22 = LD8(Wih1, 2 * HID + hid, HID, 2), Wy23 = LD8(Wih1, 2 * HID + hid, HID, 3); \
    f16x8 Wy30 = LD8(Wih1, 3 * HID + hid, HID, 0), Wy31 = LD8(Wih1, 3 * HID + hid, HID, 1); \
    f16x8 Wy32 = LD8(Wih1, 3 * HID + hid, HID, 2), Wy33 = LD8(Wih1, 3 * HID + hid, HID, 3); \
    const _Float16* pa = &y0buf[((C) - 1) & 1][col][kg * 8];                     \
    f16x8 A0 = *(const f16x8*)pa;                                                \
    f16x8 A1 = *(const f16x8*)(pa + 32);                                         \
    f16x8 A2 = *(const f16x8*)(pa + 64);                                         \
    f16x8 A3 = *(const f16x8*)(pa + 96);                                         \
    f32x4 g0 = splat4(bs10), g1 = splat4(bs11), g2 = splat4(bs12), g3 = splat4(bs13); \
    g0 = MFMA16(A0, Wy00, g0); g1 = MFMA16(A0, Wy10, g1);                        \
    g2 = MFMA16(A0, Wy20, g2); g3 = MFMA16(A0, Wy30, g3);                        \
    g0 = MFMA16(A1, Wy01, g0); g1 = MFMA16(A1, Wy11, g1);                        \
    g2 = MFMA16(A1, Wy21, g2); g3 = MFMA16(A1, Wy31, g3);                        \
    g0 = MFMA16(A2, Wy02, g0); g1 = MFMA16(A2, Wy12, g1);                        \
    g2 = MFMA16(A2, Wy22, g2); g3 = MFMA16(A2, Wy32, g3);                        \
    g0 = MFMA16(A3, Wy03, g0); g1 = MFMA16(A3, Wy13, g1);                        \
    g2 = MFMA16(A3, Wy23, g2); g3 = MFMA16(A3, Wy33, g3);                        \
    _Pragma("unroll") for (int r = 0; r < 4; ++r) {                              \
        float* d = &yacc[((kg * 4 + r) * HID + hid) * 4];                        \
        d[0] = g0[r]; d[1] = g1[r]; d[2] = g2[r]; d[3] = g3[r];                  \
    }                                                                            \
} while (0)

// ---- l0 recurrent half-step (issues 16 MFMA, ACT, writes) ----
#define L0_PART(S, P, YB)                                                        \
    f32x4 xi = *(const f32x4*)&xacc[((S) * HID + hid) * 4];                      \
    const _Float16* h0b = &h0_lds[P][0];                                         \
    f16x8 p00 = *(const f16x8*)(h0b + kg * 8);                                   \
    f16x8 p01 = *(const f16x8*)(h0b + 32 + kg * 8);                              \
    f16x8 p02 = *(const f16x8*)(h0b + 64 + kg * 8);                              \
    f16x8 p03 = *(const f16x8*)(h0b + 96 + kg * 8);                              \
    f32x4 a00 = MFMA16(p00, Wh0_00, xi);                                         \
    f32x4 a01 = MFMA16(p00, Wh0_10, splat4(xi[1]));                              \
    f32x4 a02 = MFMA16(p00, Wh0_20, splat4(xi[2]));                              \
    f32x4 a03 = MFMA16(p00, Wh0_30, splat4(xi[3]));                              \
    a00 = MFMA16(p01, Wh0_01, a00); a01 = MFMA16(p01, Wh0_11, a01);              \
    a02 = MFMA16(p01, Wh0_21, a02); a03 = MFMA16(p01, Wh0_31, a03);              \
    a00 = MFMA16(p02, Wh0_02, a00); a01 = MFMA16(p02, Wh0_12, a01);              \
    a02 = MFMA16(p02, Wh0_22, a02); a03 = MFMA16(p02, Wh0_32, a03);              \
    a00 = MFMA16(p03, Wh0_03, a00); a01 = MFMA16(p03, Wh0_13, a01);              \
    a02 = MFMA16(p03, Wh0_23, a02); a03 = MFMA16(p03, Wh0_33, a03);

#define L0_FINISH(S, P, YB)                                                      \
    float iv0 = sig_(a00[0]), fv0 = sig_(a01[0]);                                \
    float gv0 = tanh_(a02[0]), ov0 = sig_(a03[0]);                               \
    cc0 = fmaf(fv0, cc0, iv0 * gv0);                                             \
    hv0 = ov0 * tanh_(cc0);                                                      \
    if (kg == 0) {                                                               \
        _Float16 hh0 = (_Float16)hv0;                                            \
        h0_lds[(P) ^ 1][hid] = hh0;                                              \
        y0buf[YB][S][hid]    = hh0;                                              \
    }

#define L1_PART(S, P)                                                            \
    f32x4 yi = *(const f32x4*)&yacc[((S) * HID + hid) * 4];                      \
    const _Float16* h1b = &h1_lds[P][0];                                         \
    f16x8 q00 = *(const f16x8*)(h1b + kg * 8);                                   \
    f16x8 q01 = *(const f16x8*)(h1b + 32 + kg * 8);                              \
    f16x8 q02 = *(const f16x8*)(h1b + 64 + kg * 8);                              \
    f16x8 q03 = *(const f16x8*)(h1b + 96 + kg * 8);                              \
    f32x4 a10 = MFMA16(q00, Wh1_00, yi);                                         \
    f32x4 a11 = MFMA16(q00, Wh1_10, splat4(yi[1]));                              \
    f32x4 a12 = MFMA16(q00, Wh1_20, splat4(yi[2]));                              \
    f32x4 a13 = MFMA16(q00, Wh1_30, splat4(yi[3]));                              \
    a10 = MFMA16(q01, Wh1_01, a10); a11 = MFMA16(q01, Wh1_11, a11);              \
    a12 = MFMA16(q01, Wh1_21, a12); a13 = MFMA16(q01, Wh1_31, a13);              \
    a10 = MFMA16(q02, Wh1_02, a10); a11 = MFMA16(q02, Wh1_12, a11);              \
    a12 = MFMA16(q02, Wh1_22, a12); a13 = MFMA16(q02, Wh1_32, a13);              \
    a10 = MFMA16(q03, Wh1_03, a10); a11 = MFMA16(q03, Wh1_13, a11);              \
    a12 = MFMA16(q03, Wh1_23, a12); a13 = MFMA16(q03, Wh1_33, a13);

#define L1_FINISH(P)                                                             \
    float iv1 = sig_(a10[0]), fv1 = sig_(a11[0]);                                \
    float gv1 = tanh_(a12[0]), ov1 = sig_(a13[0]);                               \
    cc1 = fmaf(fv1, cc1, iv1 * gv1);                                             \
    hv1 = ov1 * tanh_(cc1);                                                      \
    if (kg == 0) h1_lds[(P) ^ 1][hid] = (_Float16)hv1;

#define STEP_BOTH(S, P, YB) do {                                                 \
    L0_PART(S, P, YB)                                                            \
    L1_PART(S, P)                                                                \
    L0_FINISH(S, P, YB)                                                          \
    L1_FINISH(P)                                                                 \
    BARRIER();                                                                   \
} while (0)

#define STEP_L0(S, P, YB) do {                                                   \
    L0_PART(S, P, YB)                                                            \
    L0_FINISH(S, P, YB)                                                          \
    BARRIER();                                                                   \
} while (0)

#define STEP_L1(S, P) do {                                                       \
    L1_PART(S, P)                                                                \
    L1_FINISH(P)                                                                 \
    BARRIER();                                                                   \
} while (0)

    // ---- chunk 0: layer 0 only ----
    XPROJ(0);
    BARRIER();
    for (int s = 0; s < SC; s += 2) {
        STEP_L0(s,     0, 0);
        STEP_L0(s + 1, 1, 0);
    }
    // ---- chunks 1..31: both layers (l1 one chunk behind) ----
    for (int c = 1; c < NCH; ++c) {
        XPROJ(c);
        YPROJ(c);
        BARRIER();
        const int yb = c & 1;
        for (int s = 0; s < SC; s += 2) {
            STEP_BOTH(s,     0, yb);
            STEP_BOTH(s + 1, 1, yb);
        }
    }
    // ---- chunk 32: layer 1 only ----
    YPROJ(NCH);
    BARRIER();
    for (int s = 0; s < SC; s += 2) {
        STEP_L1(s,     0);
        STEP_L1(s + 1, 1);
    }

    // ---- fused FC: out[b][o] = h1_final · Wfc[o] + bfc[o] ----
    if (kg == 0) xacc[hid] = hv1;     // reuse xacc as f32 h1 buffer
    BARRIER();
    if (tid < NOUT) {
        const float4* w  = (const float4*)(Wfc + (size_t)tid * HID);
        const float4* hvv = (const float4*)xacc;
        float acc = bfc[tid];
        #pragma unroll
        for (int q = 0; q < HID / 4; ++q) {
            float4 wv = w[q]; float4 h4 = hvv[q];
            acc = fmaf(wv.x, h4.x, fmaf(wv.y, h4.y, fmaf(wv.z, h4.z, fmaf(wv.w, h4.w, acc))));
        }
        out[(size_t)b * NOUT + tid] = acc;
    }
}

extern "C" void kernel_launch(void* const* d_in, const int* in_sizes, int n_in,
                              void* d_out, int out_size, void* d_ws, size_t ws_size,
                              hipStream_t stream) {
    const float* x    = (const float*)d_in[0];
    const float* Wih0 = (const float*)d_in[1];
    const float* Whh0 = (const float*)d_in[2];
    const float* bih0 = (const float*)d_in[3];
    const float* bhh0 = (const float*)d_in[4];
    const float* Wih1 = (const float*)d_in[5];
    const float* Whh1 = (const float*)d_in[6];
    const float* bih1 = (const float*)d_in[7];
    const float* bhh1 = (const float*)d_in[8];
    const float* Wfc  = (const float*)d_in[9];
    const float* bfc  = (const float*)d_in[10];
    float* out = (float*)d_out;

    lstm_fused<<<BATCH, 512, 0, stream>>>(x, Wih0, Whh0, bih0, bhh0,
                                          Wih1, Whh1, bih1, bhh1, Wfc, bfc, out);
}